// Round 9
// baseline (257.292 us; speedup 1.0000x reference)
//
#include <hip/hip_runtime.h>
#include <math.h>

namespace {

typedef __bf16 bf16x8 __attribute__((ext_vector_type(8)));
typedef __bf16 bf16x4 __attribute__((ext_vector_type(4)));
typedef float  f32x4  __attribute__((ext_vector_type(4)));
typedef float  f32x2  __attribute__((ext_vector_type(2)));

constexpr int B_      = 65536;
constexpr int OBS_DIM_= 85;
constexpr int NL_     = 5;
constexpr int NT_     = 10;
constexpr int HID_    = 64;
constexpr int NACT_   = 5;
constexpr float ALPHA_= 0.01f;

__device__ __forceinline__ float leaky(float x)    { return x > 0.0f ? x : ALPHA_ * x; }
__device__ __forceinline__ float sigmoidf(float x) { return 1.0f / (1.0f + __expf(-x)); }
__device__ __forceinline__ float tanh_fast(float x){ return 1.0f - 2.0f / (__expf(2.0f * x) + 1.0f); }

// ---------------------------------------------------------------------------
// Prep: Wa = W@a  ((h_mix@W)@a == h_mix@(W@a): kills the 64x64 matmul), plus
// bf16 weights for the MFMA kernel. ws: [0,512) Wa f32; Wih; Whh; Wf1T(64x96).
// ---------------------------------------------------------------------------
__global__ void prep_kernel(const float* __restrict__ W, const float* __restrict__ a,
                            const float* __restrict__ w_ih, const float* __restrict__ w_hh,
                            const float* __restrict__ w_fc1, void* __restrict__ ws) {
  float* Wa   = (float*)ws;
  __bf16* ih  = (__bf16*)((char*)ws + 512);
  __bf16* hh  = ih + 192 * 64;
  __bf16* f1t = hh + 192 * 64;
  const int tid = blockIdx.x * 256 + threadIdx.x;
  if (blockIdx.x == 0 && threadIdx.x < 64) {
    const int i = threadIdx.x;
    float s1 = 0.0f, s2 = 0.0f;
    #pragma unroll
    for (int j = 0; j < 64; ++j) {
      float w = W[i * 64 + j];
      s1 += w * a[j];
      s2 += w * a[64 + j];
    }
    Wa[i] = s1;
    Wa[64 + i] = s2;
  }
  const int stride = gridDim.x * 256;
  for (int i = tid; i < 192 * 64; i += stride) {
    ih[i] = (__bf16)w_ih[i];
    hh[i] = (__bf16)w_hh[i];
  }
  for (int i = tid; i < 64 * 96; i += stride) {
    int n = i / 96, k = i - 96 * n;
    f1t[i] = (__bf16)(k < 90 ? w_fc1[k * 64 + n] : 0.0f);
  }
}

// ======================= FRONT KERNEL =======================
// 32 lanes/row, 8 rows/block. r8 lesson kept: per-t scalars butterflied
// immediately into LDS (no p1[10]/p2[10] register arrays -> no spill).
// r9 change: ALL weights (stage-1 + MLP, transposed) staged in LDS once per
// block -- kills ~130 lane-varying global loads + their 64-bit addr VALU.

#define STAGE1(CI, T0, T1)                                                   \
  {                                                                          \
    const f32x2 bb = *(const f32x2*)&s_bin[CI][u0];                          \
    f32x2 w0 = *(const f32x2*)&s_win[CI][0][u0];                             \
    f32x2 w1 = *(const f32x2*)&s_win[CI][1][u0];                             \
    f32x2 w2 = *(const f32x2*)&s_win[CI][2][u0];                             \
    f32x2 w3 = *(const f32x2*)&s_win[CI][3][u0];                             \
    f32x2 w4 = *(const f32x2*)&s_win[CI][4][u0];                             \
    f32x2 w5 = *(const f32x2*)&s_win[CI][5][u0];                             \
    f32x2 w6 = *(const f32x2*)&s_win[CI][6][u0];                             \
    f32x2 w7 = *(const f32x2*)&s_win[CI][7][u0];                             \
    _Pragma("unroll")                                                        \
    for (int t = T0; t < T1; ++t) {                                          \
      const int ia = t * 8 + 4;                                              \
      const int ib = (t * 8 + 8) % 80;                                       \
      f32x4 oa = *(const f32x4*)&orow[ia];                                   \
      f32x4 ob = *(const f32x4*)&orow[ib];                                   \
      float z0 = bb[0], z1 = bb[1];                                          \
      z0 += oa[0]*w0[0] + oa[1]*w1[0] + oa[2]*w2[0] + oa[3]*w3[0]            \
          + ob[0]*w4[0] + ob[1]*w5[0] + ob[2]*w6[0] + ob[3]*w7[0];           \
      z1 += oa[0]*w0[1] + oa[1]*w1[1] + oa[2]*w2[1] + oa[3]*w3[1]            \
          + ob[0]*w4[1] + ob[1]*w5[1] + ob[2]*w6[1] + ob[3]*w7[1];           \
      float h0 = leaky(z0), h1 = leaky(z1);                                  \
      float p1t = h0 * wa1a + h1 * wa1b;                                     \
      float p2t = h0 * wa2a + h1 * wa2b;                                     \
      p1t += __shfl_xor(p1t, 1, 64);   p2t += __shfl_xor(p2t, 1, 64);        \
      p1t += __shfl_xor(p1t, 2, 64);   p2t += __shfl_xor(p2t, 2, 64);        \
      p1t += __shfl_xor(p1t, 4, 64);   p2t += __shfl_xor(p2t, 4, 64);        \
      p1t += __shfl_xor(p1t, 8, 64);   p2t += __shfl_xor(p2t, 8, 64);        \
      p1t += __shfl_xor(p1t, 16, 64);  p2t += __shfl_xor(p2t, 16, 64);       \
      if (lane32 == 0) { s_wh1[rloc][t] = p1t; s_wh2[rloc][t] = p2t; }       \
    }                                                                        \
  }

__global__ __launch_bounds__(256) void front_kernel(
    const float* __restrict__ obs,
    const float* __restrict__ w_in0, const float* __restrict__ b_in0,
    const float* __restrict__ w_in1, const float* __restrict__ b_in1,
    const float* __restrict__ w_in2, const float* __restrict__ b_in2,
    const float* __restrict__ w_o1, const float* __restrict__ b_o1,
    const float* __restrict__ w_o2, const float* __restrict__ b_o2,
    const float* __restrict__ w_o3, const float* __restrict__ b_o3,
    const float* __restrict__ Wa,
    float* __restrict__ out5) {

  __shared__ __align__(16) float s_obs[8][84];
  __shared__ __align__(16) float s_win[3][8][64];   // stage-1 weights
  __shared__ __align__(16) float s_bin[3][64];
  __shared__ __align__(16) float s_wa[128];
  __shared__ __align__(16) float s_w1t[32][12];     // w_o1^T: [unit][k]
  __shared__ __align__(16) float s_w2t[16][36];     // w_o2^T: [unit][k], stride 36
  __shared__ float s_b1[32], s_b2[16], s_w3[16];
  __shared__ float s_wh1[8][12], s_wh2[8][12];
  __shared__ float s_colm[8][6], s_cols[8][6];
  __shared__ __align__(16) float s_att[8][5][12];
  __shared__ __align__(16) float s_h1[8][5][36];
  __shared__ __align__(16) float s_h2[8][5][20];
  __shared__ float s_hp[8][6];

  const int tid    = threadIdx.x;
  const int lane   = tid & 63;
  const int lane32 = lane & 31;
  const int rloc   = tid >> 5;              // 0..7 (two rows per wave)
  const long gr0   = (long)blockIdx.x * 8;

  // ---- block-wide staging (coalesced), one barrier ----
  {
    const float* src = obs + gr0 * OBS_DIM_;
    for (int i = tid; i < 8 * 80; i += 256) {
      int r = i / 80, c = i - 80 * r;
      s_obs[r][c] = src[r * OBS_DIM_ + c];
    }
    for (int i = tid; i < 1536; i += 256) {         // 3 classes x 8 x 64, flat
      int c = i >> 9, rem = i & 511;
      const float* wc = (c == 0) ? w_in0 : (c == 1) ? w_in1 : w_in2;
      ((float*)s_win)[i] = wc[rem];
    }
    for (int i = tid; i < 512; i += 256) {          // w_o2^T
      int k = i >> 4, c = i & 15;
      s_w2t[c][k] = w_o2[i];
    }
    for (int i = tid; i < 320; i += 256) {          // w_o1^T
      int k = i >> 5, u = i & 31;
      s_w1t[u][k] = w_o1[i];
    }
    if (tid < 128) s_wa[tid] = Wa[tid];
    if (tid < 192) {
      const int c = tid >> 6, i = tid & 63;
      s_bin[c][i] = (c == 0) ? b_in0[i] : (c == 1) ? b_in1[i] : b_in2[i];
    }
    else if (tid < 224) s_b1[tid - 192] = b_o1[tid - 192];
    else if (tid < 240) s_b2[tid - 224] = b_o2[tid - 224];
    else                s_w3[tid - 240] = w_o3[tid - 240];
  }
  __syncthreads();

  const int u0 = lane32 * 2;
  const float* orow = s_obs[rloc];
  const float wa1a = s_wa[u0],      wa1b = s_wa[u0 + 1];
  const float wa2a = s_wa[64 + u0], wa2b = s_wa[64 + u0 + 1];

  STAGE1(0, 0, 5)
  STAGE1(1, 5, 9)
  STAGE1(2, 9, 10)

  // lanes 5..9: att1 column softmax stats for column jj = lane32-5
  if (lane32 >= 5 && lane32 < 10) {
    const int jj = lane32 - 5;
    float w1v = s_wh1[rloc][NL_ + jj];
    float ev[NL_], m = -1e30f;
    #pragma unroll
    for (int k = 0; k < NL_; ++k) { ev[k] = leaky(w1v + s_wh2[rloc][k]); m = fmaxf(m, ev[k]); }
    float s = 0.0f;
    #pragma unroll
    for (int k = 0; k < NL_; ++k) s += __expf(ev[k] - m);
    s_colm[rloc][jj] = m;
    s_cols[rloc][jj] = s;
  }

  // lanes 0..4: attention row r = lane32 -> s_att
  if (lane32 < NL_) {
    const int r = lane32;
    const float wh1_r = s_wh1[rloc][r];
    const float wh2_r = s_wh2[rloc][r];
    float ev[NL_], m = -1e30f;
    #pragma unroll
    for (int j = 0; j < NL_; ++j) { ev[j] = leaky(wh1_r + s_wh2[rloc][NL_ + j]); m = fmaxf(m, ev[j]); }
    float a0[NL_], s = 0.0f;
    #pragma unroll
    for (int j = 0; j < NL_; ++j) { a0[j] = __expf(ev[j] - m); s += a0[j]; }
    float inv = 1.0f / s;
    #pragma unroll
    for (int j = 0; j < NL_; ++j) s_att[rloc][r][j] = a0[j] * inv;
    #pragma unroll
    for (int jj = 0; jj < NL_; ++jj) {
      float e = leaky(s_wh1[rloc][NL_ + jj] + wh2_r);
      s_att[rloc][r][NL_ + jj] = __expf(e - s_colm[rloc][jj]) / s_cols[rloc][jj];
    }
  }

  // h1: lane owns unit lane32; w_o1 column hoisted to 10 regs (const-offset
  // ds_reads), reused across all 5 att-rows.
  {
    float w1c[NT_];
    #pragma unroll
    for (int k = 0; k < NT_; ++k) w1c[k] = s_w1t[lane32][k];
    const float b1 = s_b1[lane32];
    #pragma unroll
    for (int r5 = 0; r5 < NL_; ++r5) {
      float z = b1;
      #pragma unroll
      for (int k = 0; k < NT_; ++k) z += s_att[rloc][r5][k] * w1c[k];
      s_h1[rloc][r5][lane32] = leaky(z);
    }
  }

  // h2: 5 x 16 = 80 items over 32 lanes; weights from LDS (const-strided)
  #pragma unroll
  for (int b0 = 0; b0 < 3; ++b0) {
    int it = b0 * 32 + lane32;
    if (it < 80) {
      int r5 = it >> 4, c = it & 15;
      float z = s_b2[c];
      #pragma unroll
      for (int k = 0; k < 32; ++k) z += s_h1[rloc][r5][k] * s_w2t[c][k];
      s_h2[rloc][r5][c] = leaky(z);
    }
  }

  // hp + softmax + store (lanes 0..4)
  if (lane32 < NL_) {
    float z3 = b_o3[0];                       // wave-uniform -> s_load
    #pragma unroll
    for (int k = 0; k < 16; ++k) z3 += s_h2[rloc][lane32][k] * s_w3[k];
    float hp_own = leaky(z3);
    s_hp[rloc][lane32] = hp_own;
    float m5 = -1e30f;
    #pragma unroll
    for (int j = 0; j < NL_; ++j) m5 = fmaxf(m5, s_hp[rloc][j]);
    float ssum = 0.0f;
    #pragma unroll
    for (int j = 0; j < NL_; ++j) ssum += __expf(s_hp[rloc][j] - m5);
    out5[(gr0 + rloc) * NL_ + lane32] = __expf(hp_own - m5) / ssum;
  }
}

// ======================= GEMM KERNEL (validated MFMA phase) =======================
constexpr int ROWS_ = 64;     // 4 waves x 16-row tiles
constexpr int SOB_  = 104;    // bf16 stride: 208B -> 2-way alias (free)
constexpr int SXH_  = 72;     // bf16 stride: 144B -> 2-way alias (free), 16B aligned

__global__ __launch_bounds__(256) void gemm_kernel(
    const float* __restrict__ obs, const float* __restrict__ hidden,
    const float* __restrict__ b_fc1,
    const float* __restrict__ b_ih, const float* __restrict__ b_hh,
    const float* __restrict__ w_fc2, const float* __restrict__ b_fc2,
    const void* __restrict__ wsv,
    float* q5,                       // ALIASED: obs_out (read) then q (write)
    float* __restrict__ h_out) {

  __shared__ __align__(16) __bf16 A_obs[ROWS_ * SOB_];
  __shared__ __align__(16) __bf16 A_x[ROWS_ * SXH_];

  const int tid  = threadIdx.x;
  const int wv   = tid >> 6;
  const int lane = tid & 63;
  const int l    = lane & 15;
  const int quad = lane >> 4;
  const int r0   = wv * 16;
  const long gr0 = (long)blockIdx.x * ROWS_;

  const __bf16* Wih = (const __bf16*)((const char*)wsv + 512);
  const __bf16* Whh = Wih + 192 * 64;
  const __bf16* Wf1 = Whh + 192 * 64;

  // ---- wave-local staging (no __syncthreads in this kernel) ----
  {
    const float* src = obs + (gr0 + r0) * OBS_DIM_;
    #pragma unroll
    for (int k = 0; k < 6; ++k) {
      int idx = lane + 64 * k;
      if (idx < 340) {
        f32x4 v = *(const f32x4*)&src[idx * 4];
        #pragma unroll
        for (int e = 0; e < 4; ++e) {
          int fe = idx * 4 + e;
          int rr = fe / 85, cc = fe - 85 * rr;
          A_obs[(r0 + rr) * SOB_ + cc] = (__bf16)v[e];
        }
      }
    }
    const float* o5 = q5 + (gr0 + r0) * NL_;
    for (int it = lane; it < 16 * NL_; it += 64) {
      int rr = it / NL_; int cc = it - rr * NL_;
      A_obs[(r0 + rr) * SOB_ + 85 + cc] = (__bf16)o5[it];
    }
    for (int it = lane; it < 16 * 6; it += 64) {    // zero K-pad cols 90..95
      int rr = it / 6; int cc = it - rr * 6;
      A_obs[(r0 + rr) * SOB_ + 90 + cc] = (__bf16)0.0f;
    }
  }

  const f32x4 zero4 = {0.0f, 0.0f, 0.0f, 0.0f};

  // hidden A-fragments DIRECT from global (r9: A_h LDS round-trip removed).
  // Fragment for 16x16x32: row = l, k-chunk = ks*32 + quad*8.
  bf16x8 ah[2];
  {
    const float* hrow_g = hidden + (gr0 + r0 + l) * HID_;
    #pragma unroll
    for (int ks = 0; ks < 2; ++ks) {
      f32x4 va = *(const f32x4*)&hrow_g[ks * 32 + quad * 8];
      f32x4 vb = *(const f32x4*)&hrow_g[ks * 32 + quad * 8 + 4];
      bf16x8 t;
      t[0] = (__bf16)va[0]; t[1] = (__bf16)va[1]; t[2] = (__bf16)va[2]; t[3] = (__bf16)va[3];
      t[4] = (__bf16)vb[0]; t[5] = (__bf16)vb[1]; t[6] = (__bf16)vb[2]; t[7] = (__bf16)vb[3];
      ah[ks] = t;
    }
  }

  // fc1: C[16x64] = A_obs[16x96] @ Wf1T
  f32x4 cx[4];
  #pragma unroll
  for (int nt = 0; nt < 4; ++nt) cx[nt] = zero4;
  #pragma unroll
  for (int ks = 0; ks < 3; ++ks) {
    bf16x8 af = *(const bf16x8*)&A_obs[(r0 + l) * SOB_ + ks * 32 + quad * 8];
    #pragma unroll
    for (int nt = 0; nt < 4; ++nt) {
      bf16x8 bf = *(const bf16x8*)&Wf1[(nt * 16 + l) * 96 + ks * 32 + quad * 8];
      cx[nt] = __builtin_amdgcn_mfma_f32_16x16x32_bf16(af, bf, cx[nt], 0, 0, 0);
    }
  }
  #pragma unroll
  for (int nt = 0; nt < 4; ++nt) {
    float bias = b_fc1[nt * 16 + l];
    #pragma unroll
    for (int rg = 0; rg < 4; ++rg) {
      float xv = fmaxf(cx[nt][rg] + bias, 0.0f);
      A_x[(r0 + quad * 4 + rg) * SXH_ + nt * 16 + l] = (__bf16)xv;
    }
  }

  // GRU GEMMs
  bf16x8 ax[2];
  #pragma unroll
  for (int ks = 0; ks < 2; ++ks)
    ax[ks] = *(const bf16x8*)&A_x[(r0 + l) * SXH_ + ks * 32 + quad * 8];

  f32x4 crz[8], cni[4], cnh[4];
  #pragma unroll
  for (int nt = 0; nt < 8; ++nt) crz[nt] = zero4;
  #pragma unroll
  for (int nt = 0; nt < 4; ++nt) { cni[nt] = zero4; cnh[nt] = zero4; }
  #pragma unroll
  for (int nt = 0; nt < 8; ++nt) {
    #pragma unroll
    for (int ks = 0; ks < 2; ++ks) {
      bf16x8 bi = *(const bf16x8*)&Wih[(nt * 16 + l) * 64 + ks * 32 + quad * 8];
      crz[nt] = __builtin_amdgcn_mfma_f32_16x16x32_bf16(ax[ks], bi, crz[nt], 0, 0, 0);
      bf16x8 bh = *(const bf16x8*)&Whh[(nt * 16 + l) * 64 + ks * 32 + quad * 8];
      crz[nt] = __builtin_amdgcn_mfma_f32_16x16x32_bf16(ah[ks], bh, crz[nt], 0, 0, 0);
    }
  }
  #pragma unroll
  for (int nt = 0; nt < 4; ++nt) {
    #pragma unroll
    for (int ks = 0; ks < 2; ++ks) {
      bf16x8 bi = *(const bf16x8*)&Wih[(128 + nt * 16 + l) * 64 + ks * 32 + quad * 8];
      cni[nt] = __builtin_amdgcn_mfma_f32_16x16x32_bf16(ax[ks], bi, cni[nt], 0, 0, 0);
      bf16x8 bh = *(const bf16x8*)&Whh[(128 + nt * 16 + l) * 64 + ks * 32 + quad * 8];
      cnh[nt] = __builtin_amdgcn_mfma_f32_16x16x32_bf16(ah[ks], bh, cnh[nt], 0, 0, 0);
    }
  }

  // epilogue (C layout: row = quad*4+rg, col = t*16+l)
  const long grow = gr0 + r0 + quad * 4;
  float qp[4][NACT_];
  #pragma unroll
  for (int rg = 0; rg < 4; ++rg)
    #pragma unroll
    for (int c = 0; c < NACT_; ++c) qp[rg][c] = 0.0f;

  #pragma unroll
  for (int t = 0; t < 4; ++t) {
    const int ur = t * 16 + l;
    float br  = b_ih[ur] + b_hh[ur];
    float bz  = b_ih[64 + ur] + b_hh[64 + ur];
    float bin = b_ih[128 + ur], bhn = b_hh[128 + ur];
    float w0 = w_fc2[ur * 5 + 0], w1 = w_fc2[ur * 5 + 1], w2 = w_fc2[ur * 5 + 2];
    float w3 = w_fc2[ur * 5 + 3], w4 = w_fc2[ur * 5 + 4];
    #pragma unroll
    for (int rg = 0; rg < 4; ++rg) {
      float rr = sigmoidf(crz[t][rg] + br);
      float zz = sigmoidf(crz[4 + t][rg] + bz);
      float nn = tanh_fast(cni[t][rg] + bin + rr * (cnh[t][rg] + bhn));
      float hold = hidden[(grow + rg) * HID_ + ur];
      float hn = (1.0f - zz) * nn + zz * hold;
      h_out[(grow + rg) * HID_ + ur] = hn;
      qp[rg][0] += hn * w0;
      qp[rg][1] += hn * w1;
      qp[rg][2] += hn * w2;
      qp[rg][3] += hn * w3;
      qp[rg][4] += hn * w4;
    }
  }
  #pragma unroll
  for (int m = 1; m < 16; m <<= 1) {
    #pragma unroll
    for (int rg = 0; rg < 4; ++rg)
      #pragma unroll
      for (int c = 0; c < NACT_; ++c) qp[rg][c] += __shfl_xor(qp[rg][c], m, 64);
  }
  if (l < NACT_) {
    #pragma unroll
    for (int rg = 0; rg < 4; ++rg) {
      float qv = qp[rg][0];
      if (l == 1) qv = qp[rg][1];
      if (l == 2) qv = qp[rg][2];
      if (l == 3) qv = qp[rg][3];
      if (l == 4) qv = qp[rg][4];
      q5[(grow + rg) * NACT_ + l] = qv + b_fc2[l];
    }
  }
}

}  // namespace

extern "C" void kernel_launch(void* const* d_in, const int* in_sizes, int n_in,
                              void* d_out, int out_size, void* d_ws, size_t ws_size,
                              hipStream_t stream) {
  const float* obs    = (const float*)d_in[0];
  const float* hidden = (const float*)d_in[1];
  const float* w_in0  = (const float*)d_in[2];
  const float* b_in0  = (const float*)d_in[3];
  const float* w_in1  = (const float*)d_in[4];
  const float* b_in1  = (const float*)d_in[5];
  const float* w_in2  = (const float*)d_in[6];
  const float* b_in2  = (const float*)d_in[7];
  const float* W      = (const float*)d_in[8];
  const float* a      = (const float*)d_in[9];
  const float* w_o1   = (const float*)d_in[10];
  const float* b_o1   = (const float*)d_in[11];
  const float* w_o2   = (const float*)d_in[12];
  const float* b_o2   = (const float*)d_in[13];
  const float* w_o3   = (const float*)d_in[14];
  const float* b_o3   = (const float*)d_in[15];
  const float* w_fc1  = (const float*)d_in[16];
  const float* b_fc1  = (const float*)d_in[17];
  const float* w_ih   = (const float*)d_in[18];
  const float* w_hh   = (const float*)d_in[19];
  const float* b_ih   = (const float*)d_in[20];
  const float* b_hh   = (const float*)d_in[21];
  const float* w_fc2  = (const float*)d_in[22];
  const float* b_fc2  = (const float*)d_in[23];

  float* q_out = (float*)d_out;                  // (B,5) -- also obs_out scratch
  float* h_out = q_out + (long)B_ * NACT_;       // (B,64)
  const float* Wa = (const float*)d_ws;

  prep_kernel<<<48, 256, 0, stream>>>(W, a, w_ih, w_hh, w_fc1, d_ws);
  front_kernel<<<B_ / 8, 256, 0, stream>>>(
      obs, w_in0, b_in0, w_in1, b_in1, w_in2, b_in2,
      w_o1, b_o1, w_o2, b_o2, w_o3, b_o3, Wa, q_out);
  gemm_kernel<<<B_ / ROWS_, 256, 0, stream>>>(
      obs, hidden, b_fc1, b_ih, b_hh, w_fc2, b_fc2, d_ws, q_out, h_out);
}

// Round 10
// 236.989 us; speedup vs baseline: 1.0857x; 1.0857x over previous
//
#include <hip/hip_runtime.h>
#include <math.h>

namespace {

typedef __bf16 bf16x8 __attribute__((ext_vector_type(8)));
typedef float  f32x4  __attribute__((ext_vector_type(4)));
typedef float  f32x2  __attribute__((ext_vector_type(2)));

constexpr int B_      = 65536;
constexpr int OBS_DIM_= 85;
constexpr int NL_     = 5;
constexpr int NT_     = 10;
constexpr int HID_    = 64;
constexpr int NACT_   = 5;
constexpr float ALPHA_= 0.01f;

__device__ __forceinline__ float leaky(float x)    { return x > 0.0f ? x : ALPHA_ * x; }
__device__ __forceinline__ float sigmoidf(float x) { return 1.0f / (1.0f + __expf(-x)); }
__device__ __forceinline__ float tanh_fast(float x){ return 1.0f - 2.0f / (__expf(2.0f * x) + 1.0f); }

// ---------------------------------------------------------------------------
// Prep: Wa = W@a  ((h_mix@W)@a == h_mix@(W@a): kills the 64x64 matmul), plus
// bf16 weights for the MFMA kernel. ws: [0,512) Wa f32; Wih; Whh; Wf1T(64x96).
// ---------------------------------------------------------------------------
__global__ void prep_kernel(const float* __restrict__ W, const float* __restrict__ a,
                            const float* __restrict__ w_ih, const float* __restrict__ w_hh,
                            const float* __restrict__ w_fc1, void* __restrict__ ws) {
  float* Wa   = (float*)ws;
  __bf16* ih  = (__bf16*)((char*)ws + 512);
  __bf16* hh  = ih + 192 * 64;
  __bf16* f1t = hh + 192 * 64;
  const int tid = blockIdx.x * 256 + threadIdx.x;
  if (blockIdx.x == 0 && threadIdx.x < 64) {
    const int i = threadIdx.x;
    float s1 = 0.0f, s2 = 0.0f;
    #pragma unroll
    for (int j = 0; j < 64; ++j) {
      float w = W[i * 64 + j];
      s1 += w * a[j];
      s2 += w * a[64 + j];
    }
    Wa[i] = s1;
    Wa[64 + i] = s2;
  }
  const int stride = gridDim.x * 256;
  for (int i = tid; i < 192 * 64; i += stride) {
    ih[i] = (__bf16)w_ih[i];
    hh[i] = (__bf16)w_hh[i];
  }
  for (int i = tid; i < 64 * 96; i += stride) {
    int n = i / 96, k = i - 96 * n;
    f1t[i] = (__bf16)(k < 90 ? w_fc1[k * 64 + n] : 0.0f);
  }
}

// ======================= FRONT KERNEL =======================
// 32 lanes/row, 8 rows/block (r8-validated structure; r9 LDS-weight variant
// reverted -- it 20x'd bank conflicts and cut occupancy).
// r10 change: the 32-lane group splits into two 16-lane halves processing
// t and t+5 CONCURRENTLY (half0: t=0..4 all class0; half1: t=5..8 class1,
// masked reload to class2 for t=9). Butterfly is 4 levels instead of 5 and
// runs once per t-PAIR: 40 shuffles/lane vs r8's 100, same FMA count.

__global__ __launch_bounds__(256) void front_kernel(
    const float* __restrict__ obs,
    const float* __restrict__ w_in0, const float* __restrict__ b_in0,
    const float* __restrict__ w_in1, const float* __restrict__ b_in1,
    const float* __restrict__ w_in2, const float* __restrict__ b_in2,
    const float* __restrict__ w_o1, const float* __restrict__ b_o1,
    const float* __restrict__ w_o2, const float* __restrict__ b_o2,
    const float* __restrict__ w_o3, const float* __restrict__ b_o3,
    const float* __restrict__ Wa,
    float* __restrict__ out5) {

  __shared__ __align__(16) float s_obs[8][84];
  __shared__ float s_wh1[8][12], s_wh2[8][12];
  __shared__ float s_colm[8][6], s_cols[8][6];
  __shared__ float s_att[8][5][11];
  __shared__ float s_h1[8][5][33];
  __shared__ float s_h2[8][5][17];
  __shared__ float s_hp[8][6];

  const int tid    = threadIdx.x;
  const int wv     = tid >> 6;
  const int lane   = tid & 63;
  const int lane32 = lane & 31;
  const int rloc   = tid >> 5;              // 0..7 (two rows per wave)
  const long gr0   = (long)blockIdx.x * 8;

  // wave-local staging of cols 0..79 for this wave's two rows
  {
    const float* src = obs + (gr0 + 2 * wv) * OBS_DIM_;
    #pragma unroll
    for (int c0 = 0; c0 < 3; ++c0) {
      int it = c0 * 64 + lane;
      if (it < 160) {
        int r = (it >= 80) ? 1 : 0;
        int c = it - 80 * r;
        s_obs[2 * wv + r][c] = src[r * OBS_DIM_ + c];
      }
    }
  }

  const int half = lane32 >> 4;             // 0: t=0..4, 1: t=5..9
  const int l16  = lane32 & 15;
  const int u0   = l16 * 4;                 // my 4 INF units
  const float* orow = s_obs[rloc];

  const f32x4 wa1 = *(const f32x4*)&Wa[u0];
  const f32x4 wa2 = *(const f32x4*)&Wa[64 + u0];

  // class weights for this half: half0 -> class0 (covers t=0..4),
  // half1 -> class1 (covers t=5..8; reloaded to class2 before t=9)
  const float* wcA = half ? w_in1 : w_in0;
  const float* bcA = half ? b_in1 : b_in0;
  f32x4 wA[8];
  #pragma unroll
  for (int f = 0; f < 8; ++f) wA[f] = *(const f32x4*)&wcA[f * 64 + u0];
  f32x4 bA = *(const f32x4*)&bcA[u0];

  #pragma unroll
  for (int p = 0; p < 5; ++p) {
    if (p == 4 && half) {                   // masked reload: class2 for t=9
      #pragma unroll
      for (int f = 0; f < 8; ++f) wA[f] = *(const f32x4*)&w_in2[f * 64 + u0];
      bA = *(const f32x4*)&b_in2[u0];
    }
    const int t  = p + (half ? 5 : 0);
    int ia = t * 8 + 4;
    int ib = t * 8 + 8;
    if (ib >= 80) ib = 0;                   // wraps only at t=9
    f32x4 oa = *(const f32x4*)&orow[ia];
    f32x4 ob = *(const f32x4*)&orow[ib];
    f32x4 z = bA;
    #pragma unroll
    for (int f = 0; f < 4; ++f) {
      z[0] += oa[f] * wA[f][0]; z[1] += oa[f] * wA[f][1];
      z[2] += oa[f] * wA[f][2]; z[3] += oa[f] * wA[f][3];
    }
    #pragma unroll
    for (int f = 4; f < 8; ++f) {
      z[0] += ob[f - 4] * wA[f][0]; z[1] += ob[f - 4] * wA[f][1];
      z[2] += ob[f - 4] * wA[f][2]; z[3] += ob[f - 4] * wA[f][3];
    }
    float h0 = leaky(z[0]), h1 = leaky(z[1]), h2 = leaky(z[2]), h3 = leaky(z[3]);
    float p1t = h0 * wa1[0] + h1 * wa1[1] + h2 * wa1[2] + h3 * wa1[3];
    float p2t = h0 * wa2[0] + h1 * wa2[1] + h2 * wa2[2] + h3 * wa2[3];
    // butterfly within the 16-lane half (4 levels)
    p1t += __shfl_xor(p1t, 1, 64);  p2t += __shfl_xor(p2t, 1, 64);
    p1t += __shfl_xor(p1t, 2, 64);  p2t += __shfl_xor(p2t, 2, 64);
    p1t += __shfl_xor(p1t, 4, 64);  p2t += __shfl_xor(p2t, 4, 64);
    p1t += __shfl_xor(p1t, 8, 64);  p2t += __shfl_xor(p2t, 8, 64);
    if (l16 == 0) { s_wh1[rloc][t] = p1t; s_wh2[rloc][t] = p2t; }
  }

  // lanes 5..9: att1 column softmax stats for column jj = lane32-5
  if (lane32 >= 5 && lane32 < 10) {
    const int jj = lane32 - 5;
    float w1v = s_wh1[rloc][NL_ + jj];
    float ev[NL_], m = -1e30f;
    #pragma unroll
    for (int k = 0; k < NL_; ++k) { ev[k] = leaky(w1v + s_wh2[rloc][k]); m = fmaxf(m, ev[k]); }
    float s = 0.0f;
    #pragma unroll
    for (int k = 0; k < NL_; ++k) s += __expf(ev[k] - m);
    s_colm[rloc][jj] = m;
    s_cols[rloc][jj] = s;
  }

  // lanes 0..4: attention row r = lane32 -> s_att
  if (lane32 < NL_) {
    const int r = lane32;
    const float wh1_r = s_wh1[rloc][r];
    const float wh2_r = s_wh2[rloc][r];
    float ev[NL_], m = -1e30f;
    #pragma unroll
    for (int j = 0; j < NL_; ++j) { ev[j] = leaky(wh1_r + s_wh2[rloc][NL_ + j]); m = fmaxf(m, ev[j]); }
    float a0[NL_], s = 0.0f;
    #pragma unroll
    for (int j = 0; j < NL_; ++j) { a0[j] = __expf(ev[j] - m); s += a0[j]; }
    float inv = 1.0f / s;
    #pragma unroll
    for (int j = 0; j < NL_; ++j) s_att[rloc][r][j] = a0[j] * inv;
    #pragma unroll
    for (int jj = 0; jj < NL_; ++jj) {
      float e = leaky(s_wh1[rloc][NL_ + jj] + wh2_r);
      s_att[rloc][r][NL_ + jj] = __expf(e - s_colm[rloc][jj]) / s_cols[rloc][jj];
    }
  }

  // h1: 5 att-rows x 32 units, one unit per lane per row (w_o1 col CSE'd to regs)
  #pragma unroll
  for (int r5 = 0; r5 < NL_; ++r5) {
    float z = b_o1[lane32];
    #pragma unroll
    for (int k = 0; k < NT_; ++k) z += s_att[rloc][r5][k] * w_o1[k * 32 + lane32];
    s_h1[rloc][r5][lane32] = leaky(z);
  }

  // h2: 5 x 16 = 80 items over 32 lanes
  #pragma unroll
  for (int b0 = 0; b0 < 3; ++b0) {
    int it = b0 * 32 + lane32;
    if (it < 80) {
      int r5 = it >> 4, c = it & 15;
      float z = b_o2[c];
      #pragma unroll
      for (int k = 0; k < 32; ++k) z += s_h1[rloc][r5][k] * w_o2[k * 16 + c];
      s_h2[rloc][r5][c] = leaky(z);
    }
  }

  // hp + softmax + store (lanes 0..4)
  if (lane32 < NL_) {
    float z3 = b_o3[0];
    #pragma unroll
    for (int k = 0; k < 16; ++k) z3 += s_h2[rloc][lane32][k] * w_o3[k];
    float hp_own = leaky(z3);
    s_hp[rloc][lane32] = hp_own;
    float m5 = -1e30f;
    #pragma unroll
    for (int j = 0; j < NL_; ++j) m5 = fmaxf(m5, s_hp[rloc][j]);
    float ssum = 0.0f;
    #pragma unroll
    for (int j = 0; j < NL_; ++j) ssum += __expf(s_hp[rloc][j] - m5);
    out5[(gr0 + rloc) * NL_ + lane32] = __expf(hp_own - m5) / ssum;
  }
}

// ======================= GEMM KERNEL (validated MFMA phase, r9 form) =======================
constexpr int ROWS_ = 64;     // 4 waves x 16-row tiles
constexpr int SOB_  = 104;    // bf16 stride: 208B -> 2-way alias (free)
constexpr int SXH_  = 72;     // bf16 stride: 144B -> 2-way alias (free), 16B aligned

__global__ __launch_bounds__(256) void gemm_kernel(
    const float* __restrict__ obs, const float* __restrict__ hidden,
    const float* __restrict__ b_fc1,
    const float* __restrict__ b_ih, const float* __restrict__ b_hh,
    const float* __restrict__ w_fc2, const float* __restrict__ b_fc2,
    const void* __restrict__ wsv,
    float* q5,                       // ALIASED: obs_out (read) then q (write)
    float* __restrict__ h_out) {

  __shared__ __align__(16) __bf16 A_obs[ROWS_ * SOB_];
  __shared__ __align__(16) __bf16 A_x[ROWS_ * SXH_];

  const int tid  = threadIdx.x;
  const int wv   = tid >> 6;
  const int lane = tid & 63;
  const int l    = lane & 15;
  const int quad = lane >> 4;
  const int r0   = wv * 16;
  const long gr0 = (long)blockIdx.x * ROWS_;

  const __bf16* Wih = (const __bf16*)((const char*)wsv + 512);
  const __bf16* Whh = Wih + 192 * 64;
  const __bf16* Wf1 = Whh + 192 * 64;

  // ---- wave-local staging (no __syncthreads in this kernel) ----
  {
    const float* src = obs + (gr0 + r0) * OBS_DIM_;
    #pragma unroll
    for (int k = 0; k < 6; ++k) {
      int idx = lane + 64 * k;
      if (idx < 340) {
        f32x4 v = *(const f32x4*)&src[idx * 4];
        #pragma unroll
        for (int e = 0; e < 4; ++e) {
          int fe = idx * 4 + e;
          int rr = fe / 85, cc = fe - 85 * rr;
          A_obs[(r0 + rr) * SOB_ + cc] = (__bf16)v[e];
        }
      }
    }
    const float* o5 = q5 + (gr0 + r0) * NL_;
    for (int it = lane; it < 16 * NL_; it += 64) {
      int rr = it / NL_; int cc = it - rr * NL_;
      A_obs[(r0 + rr) * SOB_ + 85 + cc] = (__bf16)o5[it];
    }
    for (int it = lane; it < 16 * 6; it += 64) {    // zero K-pad cols 90..95
      int rr = it / 6; int cc = it - rr * 6;
      A_obs[(r0 + rr) * SOB_ + 90 + cc] = (__bf16)0.0f;
    }
  }

  const f32x4 zero4 = {0.0f, 0.0f, 0.0f, 0.0f};

  // hidden A-fragments DIRECT from global (A_h LDS round-trip removed).
  bf16x8 ah[2];
  {
    const float* hrow_g = hidden + (gr0 + r0 + l) * HID_;
    #pragma unroll
    for (int ks = 0; ks < 2; ++ks) {
      f32x4 va = *(const f32x4*)&hrow_g[ks * 32 + quad * 8];
      f32x4 vb = *(const f32x4*)&hrow_g[ks * 32 + quad * 8 + 4];
      bf16x8 t;
      t[0] = (__bf16)va[0]; t[1] = (__bf16)va[1]; t[2] = (__bf16)va[2]; t[3] = (__bf16)va[3];
      t[4] = (__bf16)vb[0]; t[5] = (__bf16)vb[1]; t[6] = (__bf16)vb[2]; t[7] = (__bf16)vb[3];
      ah[ks] = t;
    }
  }

  // fc1: C[16x64] = A_obs[16x96] @ Wf1T
  f32x4 cx[4];
  #pragma unroll
  for (int nt = 0; nt < 4; ++nt) cx[nt] = zero4;
  #pragma unroll
  for (int ks = 0; ks < 3; ++ks) {
    bf16x8 af = *(const bf16x8*)&A_obs[(r0 + l) * SOB_ + ks * 32 + quad * 8];
    #pragma unroll
    for (int nt = 0; nt < 4; ++nt) {
      bf16x8 bf = *(const bf16x8*)&Wf1[(nt * 16 + l) * 96 + ks * 32 + quad * 8];
      cx[nt] = __builtin_amdgcn_mfma_f32_16x16x32_bf16(af, bf, cx[nt], 0, 0, 0);
    }
  }
  #pragma unroll
  for (int nt = 0; nt < 4; ++nt) {
    float bias = b_fc1[nt * 16 + l];
    #pragma unroll
    for (int rg = 0; rg < 4; ++rg) {
      float xv = fmaxf(cx[nt][rg] + bias, 0.0f);
      A_x[(r0 + quad * 4 + rg) * SXH_ + nt * 16 + l] = (__bf16)xv;
    }
  }

  // GRU GEMMs
  bf16x8 ax[2];
  #pragma unroll
  for (int ks = 0; ks < 2; ++ks)
    ax[ks] = *(const bf16x8*)&A_x[(r0 + l) * SXH_ + ks * 32 + quad * 8];

  f32x4 crz[8], cni[4], cnh[4];
  #pragma unroll
  for (int nt = 0; nt < 8; ++nt) crz[nt] = zero4;
  #pragma unroll
  for (int nt = 0; nt < 4; ++nt) { cni[nt] = zero4; cnh[nt] = zero4; }
  #pragma unroll
  for (int nt = 0; nt < 8; ++nt) {
    #pragma unroll
    for (int ks = 0; ks < 2; ++ks) {
      bf16x8 bi = *(const bf16x8*)&Wih[(nt * 16 + l) * 64 + ks * 32 + quad * 8];
      crz[nt] = __builtin_amdgcn_mfma_f32_16x16x32_bf16(ax[ks], bi, crz[nt], 0, 0, 0);
      bf16x8 bh = *(const bf16x8*)&Whh[(nt * 16 + l) * 64 + ks * 32 + quad * 8];
      crz[nt] = __builtin_amdgcn_mfma_f32_16x16x32_bf16(ah[ks], bh, crz[nt], 0, 0, 0);
    }
  }
  #pragma unroll
  for (int nt = 0; nt < 4; ++nt) {
    #pragma unroll
    for (int ks = 0; ks < 2; ++ks) {
      bf16x8 bi = *(const bf16x8*)&Wih[(128 + nt * 16 + l) * 64 + ks * 32 + quad * 8];
      cni[nt] = __builtin_amdgcn_mfma_f32_16x16x32_bf16(ax[ks], bi, cni[nt], 0, 0, 0);
      bf16x8 bh = *(const bf16x8*)&Whh[(128 + nt * 16 + l) * 64 + ks * 32 + quad * 8];
      cnh[nt] = __builtin_amdgcn_mfma_f32_16x16x32_bf16(ah[ks], bh, cnh[nt], 0, 0, 0);
    }
  }

  // epilogue (C layout: row = quad*4+rg, col = t*16+l)
  const long grow = gr0 + r0 + quad * 4;
  float qp[4][NACT_];
  #pragma unroll
  for (int rg = 0; rg < 4; ++rg)
    #pragma unroll
    for (int c = 0; c < NACT_; ++c) qp[rg][c] = 0.0f;

  #pragma unroll
  for (int t = 0; t < 4; ++t) {
    const int ur = t * 16 + l;
    float br  = b_ih[ur] + b_hh[ur];
    float bz  = b_ih[64 + ur] + b_hh[64 + ur];
    float bin = b_ih[128 + ur], bhn = b_hh[128 + ur];
    float w0 = w_fc2[ur * 5 + 0], w1 = w_fc2[ur * 5 + 1], w2 = w_fc2[ur * 5 + 2];
    float w3 = w_fc2[ur * 5 + 3], w4 = w_fc2[ur * 5 + 4];
    #pragma unroll
    for (int rg = 0; rg < 4; ++rg) {
      float rr = sigmoidf(crz[t][rg] + br);
      float zz = sigmoidf(crz[4 + t][rg] + bz);
      float nn = tanh_fast(cni[t][rg] + bin + rr * (cnh[t][rg] + bhn));
      float hold = hidden[(grow + rg) * HID_ + ur];
      float hn = (1.0f - zz) * nn + zz * hold;
      h_out[(grow + rg) * HID_ + ur] = hn;
      qp[rg][0] += hn * w0;
      qp[rg][1] += hn * w1;
      qp[rg][2] += hn * w2;
      qp[rg][3] += hn * w3;
      qp[rg][4] += hn * w4;
    }
  }
  #pragma unroll
  for (int m = 1; m < 16; m <<= 1) {
    #pragma unroll
    for (int rg = 0; rg < 4; ++rg)
      #pragma unroll
      for (int c = 0; c < NACT_; ++c) qp[rg][c] += __shfl_xor(qp[rg][c], m, 64);
  }
  if (l < NACT_) {
    #pragma unroll
    for (int rg = 0; rg < 4; ++rg) {
      float qv = qp[rg][0];
      if (l == 1) qv = qp[rg][1];
      if (l == 2) qv = qp[rg][2];
      if (l == 3) qv = qp[rg][3];
      if (l == 4) qv = qp[rg][4];
      q5[(grow + rg) * NACT_ + l] = qv + b_fc2[l];
    }
  }
}

}  // namespace

extern "C" void kernel_launch(void* const* d_in, const int* in_sizes, int n_in,
                              void* d_out, int out_size, void* d_ws, size_t ws_size,
                              hipStream_t stream) {
  const float* obs    = (const float*)d_in[0];
  const float* hidden = (const float*)d_in[1];
  const float* w_in0  = (const float*)d_in[2];
  const float* b_in0  = (const float*)d_in[3];
  const float* w_in1  = (const float*)d_in[4];
  const float* b_in1  = (const float*)d_in[5];
  const float* w_in2  = (const float*)d_in[6];
  const float* b_in2  = (const float*)d_in[7];
  const float* W      = (const float*)d_in[8];
  const float* a      = (const float*)d_in[9];
  const float* w_o1   = (const float*)d_in[10];
  const float* b_o1   = (const float*)d_in[11];
  const float* w_o2   = (const float*)d_in[12];
  const float* b_o2   = (const float*)d_in[13];
  const float* w_o3   = (const float*)d_in[14];
  const float* b_o3   = (const float*)d_in[15];
  const float* w_fc1  = (const float*)d_in[16];
  const float* b_fc1  = (const float*)d_in[17];
  const float* w_ih   = (const float*)d_in[18];
  const float* w_hh   = (const float*)d_in[19];
  const float* b_ih   = (const float*)d_in[20];
  const float* b_hh   = (const float*)d_in[21];
  const float* w_fc2  = (const float*)d_in[22];
  const float* b_fc2  = (const float*)d_in[23];

  float* q_out = (float*)d_out;                  // (B,5) -- also obs_out scratch
  float* h_out = q_out + (long)B_ * NACT_;       // (B,64)
  const float* Wa = (const float*)d_ws;

  prep_kernel<<<48, 256, 0, stream>>>(W, a, w_ih, w_hh, w_fc1, d_ws);
  front_kernel<<<B_ / 8, 256, 0, stream>>>(
      obs, w_in0, b_in0, w_in1, b_in1, w_in2, b_in2,
      w_o1, b_o1, w_o2, b_o2, w_o3, b_o3, Wa, q_out);
  gemm_kernel<<<B_ / ROWS_, 256, 0, stream>>>(
      obs, hidden, b_fc1, b_ih, b_hh, w_fc2, b_fc2, d_ws, q_out, h_out);
}

// Round 11
// 206.239 us; speedup vs baseline: 1.2475x; 1.1491x over previous
//
#include <hip/hip_runtime.h>
#include <math.h>

namespace {

typedef __bf16 bf16x8 __attribute__((ext_vector_type(8)));
typedef float  f32x4  __attribute__((ext_vector_type(4)));
typedef float  f32x2  __attribute__((ext_vector_type(2)));

constexpr int B_      = 65536;
constexpr int OBS_DIM_= 85;
constexpr int NL_     = 5;
constexpr int NT_     = 10;
constexpr int HID_    = 64;
constexpr int NACT_   = 5;
constexpr float ALPHA_= 0.01f;

// 2-inst leaky: x>0 -> min(x,0)=0 -> x ; x<0 -> x + (a-1)x = a*x
__device__ __forceinline__ float leaky(float x)    { return fmaf(fminf(x, 0.0f), ALPHA_ - 1.0f, x); }
__device__ __forceinline__ float sigmoidf(float x) { return 1.0f / (1.0f + __expf(-x)); }
__device__ __forceinline__ float tanh_fast(float x){ return 1.0f - 2.0f / (__expf(2.0f * x) + 1.0f); }

// ---------------------------------------------------------------------------
// Prep: Wa = W@a  ((h_mix@W)@a == h_mix@(W@a): kills the 64x64 matmul), plus
// bf16 weights for the MFMA kernel. ws: [0,512) Wa f32; Wih; Whh; Wf1T(64x96).
// ---------------------------------------------------------------------------
__global__ void prep_kernel(const float* __restrict__ W, const float* __restrict__ a,
                            const float* __restrict__ w_ih, const float* __restrict__ w_hh,
                            const float* __restrict__ w_fc1, void* __restrict__ ws) {
  float* Wa   = (float*)ws;
  __bf16* ih  = (__bf16*)((char*)ws + 512);
  __bf16* hh  = ih + 192 * 64;
  __bf16* f1t = hh + 192 * 64;
  const int tid = blockIdx.x * 256 + threadIdx.x;
  if (blockIdx.x == 0 && threadIdx.x < 64) {
    const int i = threadIdx.x;
    float s1 = 0.0f, s2 = 0.0f;
    #pragma unroll
    for (int j = 0; j < 64; ++j) {
      float w = W[i * 64 + j];
      s1 += w * a[j];
      s2 += w * a[64 + j];
    }
    Wa[i] = s1;
    Wa[64 + i] = s2;
  }
  const int stride = gridDim.x * 256;
  for (int i = tid; i < 192 * 64; i += stride) {
    ih[i] = (__bf16)w_ih[i];
    hh[i] = (__bf16)w_hh[i];
  }
  for (int i = tid; i < 64 * 96; i += stride) {
    int n = i / 96, k = i - 96 * n;
    f1t[i] = (__bf16)(k < 90 ? w_fc1[k * 64 + n] : 0.0f);
  }
}

// ======================= FRONT KERNEL =======================
// r11: 16 lanes/row (4 INF units each), 16 rows/block, grid 4096 -- HALF the
// waves of r10. Per-wave fixed sections (attention/MLP/softmax, exec-masked)
// now cover 4 rows per issue instead of 2. Stage-1 keeps the r8 no-spill
// invariant: per-t scalars butterflied immediately into LDS, never p[10]
// register arrays. Class weights reload uniformly at t=5 and t=9.

__global__ __launch_bounds__(256) void front_kernel(
    const float* __restrict__ obs,
    const float* __restrict__ w_in0, const float* __restrict__ b_in0,
    const float* __restrict__ w_in1, const float* __restrict__ b_in1,
    const float* __restrict__ w_in2, const float* __restrict__ b_in2,
    const float* __restrict__ w_o1, const float* __restrict__ b_o1,
    const float* __restrict__ w_o2, const float* __restrict__ b_o2,
    const float* __restrict__ w_o3, const float* __restrict__ b_o3,
    const float* __restrict__ Wa,
    float* __restrict__ out5) {

  __shared__ __align__(16) float s_obs[16][84];
  __shared__ float s_wh1[16][12], s_wh2[16][12];
  __shared__ float s_colm[16][6], s_cols[16][6];
  __shared__ __align__(16) float s_att[16][5][12];  // stride 12: f32x2-aligned
  __shared__ __align__(16) float s_h1[16][5][36];   // stride 36: f32x4-aligned rows
  __shared__ __align__(16) float s_h2[16][5][20];   // stride 20: f32x4-aligned rows
  __shared__ float s_hp[16][6];

  const int tid  = threadIdx.x;
  const int wv   = tid >> 6;
  const int lane = tid & 63;
  const int l16  = lane & 15;
  const int rloc = tid >> 4;                // 0..15 (four rows per wave)
  const long gr0 = (long)blockIdx.x * 16;

  // wave-local staging: this wave's 4 rows, cols 0..79 (320 = 5*64 exactly)
  {
    const float* src = obs + (gr0 + wv * 4) * OBS_DIM_;
    #pragma unroll
    for (int c0 = 0; c0 < 5; ++c0) {
      int it = c0 * 64 + lane;
      int r = it / 80, c = it - 80 * r;
      s_obs[wv * 4 + r][c] = src[r * OBS_DIM_ + c];
    }
  }

  const int u0 = l16 * 4;                   // my 4 INF units
  const float* orow = s_obs[rloc];
  const f32x4 wa1 = *(const f32x4*)&Wa[u0];
  const f32x4 wa2 = *(const f32x4*)&Wa[64 + u0];

  // stage-1: class weights in 8 f32x4 regs, uniform reload at t=5 / t=9
  f32x4 wA[8];
  #pragma unroll
  for (int f = 0; f < 8; ++f) wA[f] = *(const f32x4*)&w_in0[f * 64 + u0];
  f32x4 bA = *(const f32x4*)&b_in0[u0];

  #pragma unroll
  for (int t = 0; t < NT_; ++t) {
    if (t == 5) {
      #pragma unroll
      for (int f = 0; f < 8; ++f) wA[f] = *(const f32x4*)&w_in1[f * 64 + u0];
      bA = *(const f32x4*)&b_in1[u0];
    }
    if (t == 9) {
      #pragma unroll
      for (int f = 0; f < 8; ++f) wA[f] = *(const f32x4*)&w_in2[f * 64 + u0];
      bA = *(const f32x4*)&b_in2[u0];
    }
    const int ia = t * 8 + 4;               // feats 0..3 (never wraps)
    int ib = t * 8 + 8;                     // feats 4..7 (wraps only at t=9)
    if (ib >= 80) ib = 0;
    f32x4 oa = *(const f32x4*)&orow[ia];
    f32x4 ob = *(const f32x4*)&orow[ib];
    f32x4 z = bA;
    #pragma unroll
    for (int f = 0; f < 4; ++f) {
      z[0] += oa[f] * wA[f][0]; z[1] += oa[f] * wA[f][1];
      z[2] += oa[f] * wA[f][2]; z[3] += oa[f] * wA[f][3];
    }
    #pragma unroll
    for (int f = 4; f < 8; ++f) {
      z[0] += ob[f - 4] * wA[f][0]; z[1] += ob[f - 4] * wA[f][1];
      z[2] += ob[f - 4] * wA[f][2]; z[3] += ob[f - 4] * wA[f][3];
    }
    float h0 = leaky(z[0]), h1 = leaky(z[1]), h2 = leaky(z[2]), h3 = leaky(z[3]);
    float p1t = h0 * wa1[0] + h1 * wa1[1] + h2 * wa1[2] + h3 * wa1[3];
    float p2t = h0 * wa2[0] + h1 * wa2[1] + h2 * wa2[2] + h3 * wa2[3];
    // butterfly within the 16-lane row group
    p1t += __shfl_xor(p1t, 1, 64);  p2t += __shfl_xor(p2t, 1, 64);
    p1t += __shfl_xor(p1t, 2, 64);  p2t += __shfl_xor(p2t, 2, 64);
    p1t += __shfl_xor(p1t, 4, 64);  p2t += __shfl_xor(p2t, 4, 64);
    p1t += __shfl_xor(p1t, 8, 64);  p2t += __shfl_xor(p2t, 8, 64);
    if (l16 == 0) { s_wh1[rloc][t] = p1t; s_wh2[rloc][t] = p2t; }
  }

  // lanes 5..9 of each group: att1 column softmax stats (column jj = l16-5)
  if (l16 >= 5 && l16 < 10) {
    const int jj = l16 - 5;
    float w1v = s_wh1[rloc][NL_ + jj];
    float ev[NL_], m = -1e30f;
    #pragma unroll
    for (int k = 0; k < NL_; ++k) { ev[k] = leaky(w1v + s_wh2[rloc][k]); m = fmaxf(m, ev[k]); }
    float s = 0.0f;
    #pragma unroll
    for (int k = 0; k < NL_; ++k) s += __expf(ev[k] - m);
    s_colm[rloc][jj] = m;
    s_cols[rloc][jj] = s;
  }

  // lanes 0..4: attention row r = l16 -> s_att
  if (l16 < NL_) {
    const int r = l16;
    const float wh1_r = s_wh1[rloc][r];
    const float wh2_r = s_wh2[rloc][r];
    float ev[NL_], m = -1e30f;
    #pragma unroll
    for (int j = 0; j < NL_; ++j) { ev[j] = leaky(wh1_r + s_wh2[rloc][NL_ + j]); m = fmaxf(m, ev[j]); }
    float a0[NL_], s = 0.0f;
    #pragma unroll
    for (int j = 0; j < NL_; ++j) { a0[j] = __expf(ev[j] - m); s += a0[j]; }
    float inv = 1.0f / s;
    #pragma unroll
    for (int j = 0; j < NL_; ++j) s_att[rloc][r][j] = a0[j] * inv;
    #pragma unroll
    for (int jj = 0; jj < NL_; ++jj) {
      float e = leaky(s_wh1[rloc][NL_ + jj] + wh2_r);
      s_att[rloc][r][NL_ + jj] = __expf(e - s_colm[rloc][jj]) / s_cols[rloc][jj];
    }
  }

  // h1: lane owns units 2*l16, 2*l16+1; w_o1 cols as 10 f32x2 regs, att rows
  // read as 5 f32x2 (stride-12 rows keep 8B alignment).
  {
    f32x2 w1c[NT_];
    #pragma unroll
    for (int k = 0; k < NT_; ++k) w1c[k] = *(const f32x2*)&w_o1[k * 32 + l16 * 2];
    const f32x2 b1 = *(const f32x2*)&b_o1[l16 * 2];
    #pragma unroll
    for (int r5 = 0; r5 < NL_; ++r5) {
      float za = b1[0], zb = b1[1];
      #pragma unroll
      for (int k2 = 0; k2 < 5; ++k2) {
        f32x2 at = *(const f32x2*)&s_att[rloc][r5][k2 * 2];
        za += at[0] * w1c[2 * k2][0] + at[1] * w1c[2 * k2 + 1][0];
        zb += at[0] * w1c[2 * k2][1] + at[1] * w1c[2 * k2 + 1][1];
      }
      *(f32x2*)&s_h1[rloc][r5][l16 * 2] = f32x2{leaky(za), leaky(zb)};
    }
  }

  // h2: lane owns unit c = l16 (exactly 16 units); w_o2 column in 32 regs,
  // h1 rows read as f32x4 (stride-36 rows keep 16B alignment).
  {
    float w2c[32];
    #pragma unroll
    for (int k = 0; k < 32; ++k) w2c[k] = w_o2[k * 16 + l16];
    const float b2 = b_o2[l16];
    #pragma unroll
    for (int r5 = 0; r5 < NL_; ++r5) {
      float z = b2;
      #pragma unroll
      for (int k4 = 0; k4 < 8; ++k4) {
        f32x4 hv = *(const f32x4*)&s_h1[rloc][r5][k4 * 4];
        z += hv[0] * w2c[4 * k4] + hv[1] * w2c[4 * k4 + 1]
           + hv[2] * w2c[4 * k4 + 2] + hv[3] * w2c[4 * k4 + 3];
      }
      s_h2[rloc][r5][l16] = leaky(z);
    }
  }

  // hp + softmax + store (lanes 0..4 of each group)
  if (l16 < NL_) {
    float z3 = b_o3[0];
    #pragma unroll
    for (int k4 = 0; k4 < 4; ++k4) {
      f32x4 hv = *(const f32x4*)&s_h2[rloc][l16][k4 * 4];
      z3 += hv[0] * w_o3[4 * k4] + hv[1] * w_o3[4 * k4 + 1]
          + hv[2] * w_o3[4 * k4 + 2] + hv[3] * w_o3[4 * k4 + 3];
    }
    float hp_own = leaky(z3);
    s_hp[rloc][l16] = hp_own;
    float m5 = -1e30f;
    #pragma unroll
    for (int j = 0; j < NL_; ++j) m5 = fmaxf(m5, s_hp[rloc][j]);
    float ssum = 0.0f;
    #pragma unroll
    for (int j = 0; j < NL_; ++j) ssum += __expf(s_hp[rloc][j] - m5);
    out5[(gr0 + rloc) * NL_ + l16] = __expf(hp_own - m5) / ssum;
  }
}

// ======================= GEMM KERNEL (validated MFMA phase, unchanged) =======================
constexpr int ROWS_ = 64;     // 4 waves x 16-row tiles
constexpr int SOB_  = 104;    // bf16 stride: 208B -> 2-way alias (free)
constexpr int SXH_  = 72;     // bf16 stride: 144B -> 2-way alias (free), 16B aligned

__global__ __launch_bounds__(256) void gemm_kernel(
    const float* __restrict__ obs, const float* __restrict__ hidden,
    const float* __restrict__ b_fc1,
    const float* __restrict__ b_ih, const float* __restrict__ b_hh,
    const float* __restrict__ w_fc2, const float* __restrict__ b_fc2,
    const void* __restrict__ wsv,
    float* q5,                       // ALIASED: obs_out (read) then q (write)
    float* __restrict__ h_out) {

  __shared__ __align__(16) __bf16 A_obs[ROWS_ * SOB_];
  __shared__ __align__(16) __bf16 A_x[ROWS_ * SXH_];

  const int tid  = threadIdx.x;
  const int wv   = tid >> 6;
  const int lane = tid & 63;
  const int l    = lane & 15;
  const int quad = lane >> 4;
  const int r0   = wv * 16;
  const long gr0 = (long)blockIdx.x * ROWS_;

  const __bf16* Wih = (const __bf16*)((const char*)wsv + 512);
  const __bf16* Whh = Wih + 192 * 64;
  const __bf16* Wf1 = Whh + 192 * 64;

  // ---- wave-local staging (no __syncthreads in this kernel) ----
  {
    const float* src = obs + (gr0 + r0) * OBS_DIM_;
    #pragma unroll
    for (int k = 0; k < 6; ++k) {
      int idx = lane + 64 * k;
      if (idx < 340) {
        f32x4 v = *(const f32x4*)&src[idx * 4];
        #pragma unroll
        for (int e = 0; e < 4; ++e) {
          int fe = idx * 4 + e;
          int rr = fe / 85, cc = fe - 85 * rr;
          A_obs[(r0 + rr) * SOB_ + cc] = (__bf16)v[e];
        }
      }
    }
    const float* o5 = q5 + (gr0 + r0) * NL_;
    for (int it = lane; it < 16 * NL_; it += 64) {
      int rr = it / NL_; int cc = it - rr * NL_;
      A_obs[(r0 + rr) * SOB_ + 85 + cc] = (__bf16)o5[it];
    }
    for (int it = lane; it < 16 * 6; it += 64) {    // zero K-pad cols 90..95
      int rr = it / 6; int cc = it - rr * 6;
      A_obs[(r0 + rr) * SOB_ + 90 + cc] = (__bf16)0.0f;
    }
  }

  const f32x4 zero4 = {0.0f, 0.0f, 0.0f, 0.0f};

  // hidden A-fragments DIRECT from global (A_h LDS round-trip removed).
  bf16x8 ah[2];
  {
    const float* hrow_g = hidden + (gr0 + r0 + l) * HID_;
    #pragma unroll
    for (int ks = 0; ks < 2; ++ks) {
      f32x4 va = *(const f32x4*)&hrow_g[ks * 32 + quad * 8];
      f32x4 vb = *(const f32x4*)&hrow_g[ks * 32 + quad * 8 + 4];
      bf16x8 t;
      t[0] = (__bf16)va[0]; t[1] = (__bf16)va[1]; t[2] = (__bf16)va[2]; t[3] = (__bf16)va[3];
      t[4] = (__bf16)vb[0]; t[5] = (__bf16)vb[1]; t[6] = (__bf16)vb[2]; t[7] = (__bf16)vb[3];
      ah[ks] = t;
    }
  }

  // fc1: C[16x64] = A_obs[16x96] @ Wf1T
  f32x4 cx[4];
  #pragma unroll
  for (int nt = 0; nt < 4; ++nt) cx[nt] = zero4;
  #pragma unroll
  for (int ks = 0; ks < 3; ++ks) {
    bf16x8 af = *(const bf16x8*)&A_obs[(r0 + l) * SOB_ + ks * 32 + quad * 8];
    #pragma unroll
    for (int nt = 0; nt < 4; ++nt) {
      bf16x8 bf = *(const bf16x8*)&Wf1[(nt * 16 + l) * 96 + ks * 32 + quad * 8];
      cx[nt] = __builtin_amdgcn_mfma_f32_16x16x32_bf16(af, bf, cx[nt], 0, 0, 0);
    }
  }
  #pragma unroll
  for (int nt = 0; nt < 4; ++nt) {
    float bias = b_fc1[nt * 16 + l];
    #pragma unroll
    for (int rg = 0; rg < 4; ++rg) {
      float xv = fmaxf(cx[nt][rg] + bias, 0.0f);
      A_x[(r0 + quad * 4 + rg) * SXH_ + nt * 16 + l] = (__bf16)xv;
    }
  }

  // GRU GEMMs
  bf16x8 ax[2];
  #pragma unroll
  for (int ks = 0; ks < 2; ++ks)
    ax[ks] = *(const bf16x8*)&A_x[(r0 + l) * SXH_ + ks * 32 + quad * 8];

  f32x4 crz[8], cni[4], cnh[4];
  #pragma unroll
  for (int nt = 0; nt < 8; ++nt) crz[nt] = zero4;
  #pragma unroll
  for (int nt = 0; nt < 4; ++nt) { cni[nt] = zero4; cnh[nt] = zero4; }
  #pragma unroll
  for (int nt = 0; nt < 8; ++nt) {
    #pragma unroll
    for (int ks = 0; ks < 2; ++ks) {
      bf16x8 bi = *(const bf16x8*)&Wih[(nt * 16 + l) * 64 + ks * 32 + quad * 8];
      crz[nt] = __builtin_amdgcn_mfma_f32_16x16x32_bf16(ax[ks], bi, crz[nt], 0, 0, 0);
      bf16x8 bh = *(const bf16x8*)&Whh[(nt * 16 + l) * 64 + ks * 32 + quad * 8];
      crz[nt] = __builtin_amdgcn_mfma_f32_16x16x32_bf16(ah[ks], bh, crz[nt], 0, 0, 0);
    }
  }
  #pragma unroll
  for (int nt = 0; nt < 4; ++nt) {
    #pragma unroll
    for (int ks = 0; ks < 2; ++ks) {
      bf16x8 bi = *(const bf16x8*)&Wih[(128 + nt * 16 + l) * 64 + ks * 32 + quad * 8];
      cni[nt] = __builtin_amdgcn_mfma_f32_16x16x32_bf16(ax[ks], bi, cni[nt], 0, 0, 0);
      bf16x8 bh = *(const bf16x8*)&Whh[(128 + nt * 16 + l) * 64 + ks * 32 + quad * 8];
      cnh[nt] = __builtin_amdgcn_mfma_f32_16x16x32_bf16(ah[ks], bh, cnh[nt], 0, 0, 0);
    }
  }

  // epilogue (C layout: row = quad*4+rg, col = t*16+l)
  const long grow = gr0 + r0 + quad * 4;
  float qp[4][NACT_];
  #pragma unroll
  for (int rg = 0; rg < 4; ++rg)
    #pragma unroll
    for (int c = 0; c < NACT_; ++c) qp[rg][c] = 0.0f;

  #pragma unroll
  for (int t = 0; t < 4; ++t) {
    const int ur = t * 16 + l;
    float br  = b_ih[ur] + b_hh[ur];
    float bz  = b_ih[64 + ur] + b_hh[64 + ur];
    float bin = b_ih[128 + ur], bhn = b_hh[128 + ur];
    float w0 = w_fc2[ur * 5 + 0], w1 = w_fc2[ur * 5 + 1], w2 = w_fc2[ur * 5 + 2];
    float w3 = w_fc2[ur * 5 + 3], w4 = w_fc2[ur * 5 + 4];
    #pragma unroll
    for (int rg = 0; rg < 4; ++rg) {
      float rr = sigmoidf(crz[t][rg] + br);
      float zz = sigmoidf(crz[4 + t][rg] + bz);
      float nn = tanh_fast(cni[t][rg] + bin + rr * (cnh[t][rg] + bhn));
      float hold = hidden[(grow + rg) * HID_ + ur];
      float hn = (1.0f - zz) * nn + zz * hold;
      h_out[(grow + rg) * HID_ + ur] = hn;
      qp[rg][0] += hn * w0;
      qp[rg][1] += hn * w1;
      qp[rg][2] += hn * w2;
      qp[rg][3] += hn * w3;
      qp[rg][4] += hn * w4;
    }
  }
  #pragma unroll
  for (int m = 1; m < 16; m <<= 1) {
    #pragma unroll
    for (int rg = 0; rg < 4; ++rg)
      #pragma unroll
      for (int c = 0; c < NACT_; ++c) qp[rg][c] += __shfl_xor(qp[rg][c], m, 64);
  }
  if (l < NACT_) {
    #pragma unroll
    for (int rg = 0; rg < 4; ++rg) {
      float qv = qp[rg][0];
      if (l == 1) qv = qp[rg][1];
      if (l == 2) qv = qp[rg][2];
      if (l == 3) qv = qp[rg][3];
      if (l == 4) qv = qp[rg][4];
      q5[(grow + rg) * NACT_ + l] = qv + b_fc2[l];
    }
  }
}

}  // namespace

extern "C" void kernel_launch(void* const* d_in, const int* in_sizes, int n_in,
                              void* d_out, int out_size, void* d_ws, size_t ws_size,
                              hipStream_t stream) {
  const float* obs    = (const float*)d_in[0];
  const float* hidden = (const float*)d_in[1];
  const float* w_in0  = (const float*)d_in[2];
  const float* b_in0  = (const float*)d_in[3];
  const float* w_in1  = (const float*)d_in[4];
  const float* b_in1  = (const float*)d_in[5];
  const float* w_in2  = (const float*)d_in[6];
  const float* b_in2  = (const float*)d_in[7];
  const float* W      = (const float*)d_in[8];
  const float* a      = (const float*)d_in[9];
  const float* w_o1   = (const float*)d_in[10];
  const float* b_o1   = (const float*)d_in[11];
  const float* w_o2   = (const float*)d_in[12];
  const float* b_o2   = (const float*)d_in[13];
  const float* w_o3   = (const float*)d_in[14];
  const float* b_o3   = (const float*)d_in[15];
  const float* w_fc1  = (const float*)d_in[16];
  const float* b_fc1  = (const float*)d_in[17];
  const float* w_ih   = (const float*)d_in[18];
  const float* w_hh   = (const float*)d_in[19];
  const float* b_ih   = (const float*)d_in[20];
  const float* b_hh   = (const float*)d_in[21];
  const float* w_fc2  = (const float*)d_in[22];
  const float* b_fc2  = (const float*)d_in[23];

  float* q_out = (float*)d_out;                  // (B,5) -- also obs_out scratch
  float* h_out = q_out + (long)B_ * NACT_;       // (B,64)
  const float* Wa = (const float*)d_ws;

  prep_kernel<<<48, 256, 0, stream>>>(W, a, w_ih, w_hh, w_fc1, d_ws);
  front_kernel<<<B_ / 16, 256, 0, stream>>>(
      obs, w_in0, b_in0, w_in1, b_in1, w_in2, b_in2,
      w_o1, b_o1, w_o2, b_o2, w_o3, b_o3, Wa, q_out);
  gemm_kernel<<<B_ / ROWS_, 256, 0, stream>>>(
      obs, hidden, b_fc1, b_ih, b_hh, w_fc2, b_fc2, d_ws, q_out, h_out);
}